// Round 4
// baseline (289.029 us; speedup 1.0000x reference)
//
#include <hip/hip_runtime.h>
#include <stdint.h>

// Problem constants
#define BATCH 2
#define TDIM 2048
#define EDIM 2048
#define NH 16
#define HD 128
#define E3 6144
#define MROWS 4096  // BATCH*TDIM

typedef short v8bf __attribute__((ext_vector_type(8)));   // 8 bf16 bit patterns (4 VGPRs)
typedef float v4f  __attribute__((ext_vector_type(4)));

typedef __attribute__((address_space(3))) uint8_t lds_u8;
typedef __attribute__((address_space(1))) uint8_t glb_u8;

__device__ __forceinline__ void gload16(const void* g, void* l) {
    __builtin_amdgcn_global_load_lds((const glb_u8*)g, (lds_u8*)l, 16, 0, 0);
}

__device__ __forceinline__ ushort f2bf(float f) {
    uint32_t u = __float_as_uint(f);
    return (ushort)((u + 0x7fffu + ((u >> 16) & 1u)) >> 16);  // RNE
}

// ---------------- fp32 -> bf16 elementwise ----------------
__global__ void cvtx_kernel(const float* __restrict__ in, ushort* __restrict__ out, int n) {
    int i = (blockIdx.x * 256 + threadIdx.x) * 4;
    const int stride = gridDim.x * 256 * 4;
    for (; i < n; i += stride) {
        const float4 v = *reinterpret_cast<const float4*>(in + i);
        ushort4 o = make_ushort4(f2bf(v.x), f2bf(v.y), f2bf(v.z), f2bf(v.w));
        *reinterpret_cast<ushort4*>(out + i) = o;
    }
}

// ---------------- fp32 [R][C] -> bf16 [C][R] (transpose + convert) ----------------
__global__ void tcvt_kernel(const float* __restrict__ in, ushort* __restrict__ out, int R, int C) {
    __shared__ float t[32][33];
    const int tc = blockIdx.x * 32;
    const int tr = blockIdx.y * 32;
    const int tid = threadIdx.x;
    const int row = tid >> 3, c4 = (tid & 7) * 4;
    const float4 v = *reinterpret_cast<const float4*>(in + (size_t)(tr + row) * C + tc + c4);
    t[row][c4] = v.x; t[row][c4 + 1] = v.y; t[row][c4 + 2] = v.z; t[row][c4 + 3] = v.w;
    __syncthreads();
    const int oc = tid >> 3, r4 = (tid & 7) * 4;
    ushort4 o = make_ushort4(f2bf(t[r4][oc]), f2bf(t[r4 + 1][oc]),
                             f2bf(t[r4 + 2][oc]), f2bf(t[r4 + 3][oc]));
    *reinterpret_cast<ushort4*>(out + (size_t)(tc + oc) * R + tr + r4) = o;
}

// ---------------- V extract + transpose: qkv[.][4096+h*128+d] -> vt[bh][d][t] ----------------
__global__ void vtrans_kernel(const ushort* __restrict__ qkv, ushort* __restrict__ vt) {
    __shared__ ushort t[32][33];
    const int bh = blockIdx.z;
    const int b = bh >> 4, h = bh & 15;
    const int tr = blockIdx.x * 32;   // t tile
    const int tc = blockIdx.y * 32;   // d tile
    const int tid = threadIdx.x;
    const int row = tid >> 3, c4 = (tid & 7) * 4;
    const ushort4 v = *reinterpret_cast<const ushort4*>(
        qkv + (size_t)(b * TDIM + tr + row) * E3 + 2 * EDIM + h * HD + tc + c4);
    t[row][c4] = v.x; t[row][c4 + 1] = v.y; t[row][c4 + 2] = v.z; t[row][c4 + 3] = v.w;
    __syncthreads();
    const int oc = tid >> 3, r4 = (tid & 7) * 4;
    ushort4 o = make_ushort4(t[r4][oc], t[r4 + 1][oc], t[r4 + 2][oc], t[r4 + 3][oc]);
    *reinterpret_cast<ushort4*>(vt + (size_t)(bh * HD + tc + oc) * TDIM + tr + r4) = o;
}

// ---------------- GEMM1: 256x256 tile, BK=64, 8 waves, counted-vmcnt pipeline ----------------
// C[M][N] (bf16) = A[M][K] * Bt[N][K]^T. Requires M%256==0, N%256==0, K%64==0, nwg%8==0.
__global__ __launch_bounds__(512, 2) void gemm256_kernel(const ushort* __restrict__ A,
                                                         const ushort* __restrict__ Bt,
                                                         ushort* __restrict__ C,
                                                         int Mdim, int Ndim, int Kdim) {
    __shared__ __align__(16) ushort Al[2][256 * 64];   // 32 KiB each buf
    __shared__ __align__(16) ushort Bl[2][256 * 64];   // total LDS 128 KiB -> 1 block/CU
    const int tid = threadIdx.x;
    const int lane = tid & 63;
    const int wv = tid >> 6;            // 0..7
    const int l4 = lane >> 4, l16 = lane & 15;
    const int wr = wv >> 2, wc = wv & 3;   // 2 x 4 wave grid; wave tile 128x64
    const int nbn = Ndim >> 8;
    const int nwg = (Mdim >> 8) * nbn;
    int bid = blockIdx.x;
    bid = (bid & 7) * (nwg >> 3) + (bid >> 3);   // XCD swizzle (nwg % 8 == 0)
    const int bm = bid / nbn, bn = bid % nbn;

    const ushort* Abase = A + (size_t)(bm * 256) * Kdim;
    const ushort* Bbase = Bt + (size_t)(bn * 256) * Kdim;
    const int NT = Kdim >> 6;

    v4f acc[8][4] = {};

    // Stage K-tile KT into buf: 4 A-gloads + 4 B-gloads per thread (8 in flight/wave).
    // LDS[row][slot8] holds global 16B-chunk (slot ^ (row&7))  -> swizzled, conflict-free reads.
#define STAGE256(BUF, KT)                                                                     \
    do {                                                                                      \
        _Pragma("unroll") for (int i = 0; i < 4; ++i) {                                       \
            const int c = i * 512 + tid;                                                      \
            const int row = c >> 3;                                                           \
            const int kc = (c & 7) ^ (row & 7);                                               \
            gload16(Abase + (size_t)row * Kdim + (KT) * 64 + kc * 8,                          \
                    &Al[BUF][(i * 512 + wv * 64) * 8]);                                       \
        }                                                                                     \
        _Pragma("unroll") for (int i = 0; i < 4; ++i) {                                       \
            const int c = i * 512 + tid;                                                      \
            const int row = c >> 3;                                                           \
            const int kc = (c & 7) ^ (row & 7);                                               \
            gload16(Bbase + (size_t)row * Kdim + (KT) * 64 + kc * 8,                          \
                    &Bl[BUF][(i * 512 + wv * 64) * 8]);                                       \
        }                                                                                     \
    } while (0)

    STAGE256(0, 0);
    STAGE256(1, 1);
    asm volatile("s_waitcnt vmcnt(8)" ::: "memory");   // tile 0 resident (tile 1 in flight)
    __builtin_amdgcn_s_barrier();
    asm volatile("" ::: "memory");

    int cur = 0;
    for (int t = 0; t < NT; ++t) {
        const ushort* As = &Al[cur][0];
        const ushort* Bs = &Bl[cur][0];
        // 4 phases: (mh, nh) quadrants of the wave's 128x64 C-tile, 16 MFMA each
#pragma unroll
        for (int mh = 0; mh < 2; ++mh) {
            v8bf af[4][2];
#pragma unroll
            for (int m = 0; m < 4; ++m)
#pragma unroll
                for (int kk = 0; kk < 2; ++kk) {
                    const int r = wr * 128 + mh * 64 + m * 16 + l16;
                    const int slot = (kk * 4 + l4) ^ (l16 & 7);   // r&7 == l16&7
                    af[m][kk] = *reinterpret_cast<const v8bf*>(&As[r * 64 + slot * 8]);
                }
#pragma unroll
            for (int nh = 0; nh < 2; ++nh) {
                v8bf bfr[2][2];
#pragma unroll
                for (int n = 0; n < 2; ++n)
#pragma unroll
                    for (int kk = 0; kk < 2; ++kk) {
                        const int r = wc * 64 + nh * 32 + n * 16 + l16;
                        const int slot = (kk * 4 + l4) ^ (l16 & 7);
                        bfr[n][kk] = *reinterpret_cast<const v8bf*>(&Bs[r * 64 + slot * 8]);
                    }
                __builtin_amdgcn_s_setprio(1);
#pragma unroll
                for (int kk = 0; kk < 2; ++kk)
#pragma unroll
                    for (int m = 0; m < 4; ++m)
#pragma unroll
                        for (int n = 0; n < 2; ++n)
                            acc[mh * 4 + m][nh * 2 + n] = __builtin_amdgcn_mfma_f32_16x16x32_bf16(
                                af[m][kk], bfr[n][kk], acc[mh * 4 + m][nh * 2 + n], 0, 0, 0);
                __builtin_amdgcn_s_setprio(0);
            }
        }
        if (t == NT - 1) break;

        __builtin_amdgcn_sched_barrier(0);
        __builtin_amdgcn_s_barrier();              // all waves done reading buf cur
        asm volatile("" ::: "memory");
        if (t + 2 < NT) {
            STAGE256(cur, t + 2);                  // overwrite cur with tile t+2 (in flight)
            asm volatile("s_waitcnt vmcnt(8)" ::: "memory");  // tile t+1's 8 loads done
        } else {
            asm volatile("s_waitcnt vmcnt(0)" ::: "memory");
        }
        __builtin_amdgcn_s_barrier();              // buf cur^1 (tile t+1) readable by all
        asm volatile("" ::: "memory");
        __builtin_amdgcn_sched_barrier(0);
        cur ^= 1;
    }
#undef STAGE256

    // Epilogue. C/D layout: col = lane&15, row = (lane>>4)*4 + j
    const int r0 = bm * 256 + wr * 128 + l4 * 4;
    const int c0 = bn * 256 + wc * 64 + l16;
#pragma unroll
    for (int mi = 0; mi < 8; ++mi)
#pragma unroll
        for (int ni = 0; ni < 4; ++ni)
#pragma unroll
            for (int j = 0; j < 4; ++j)
                C[(size_t)(r0 + mi * 16 + j) * Ndim + c0 + ni * 16] = f2bf(acc[mi][ni][j]);
}

// ---------------- bf16 GEMM (128x128, m97-structure) -- used for GEMM2 (f32 out + bias) ----
template <int OUTF32>
__global__ void gemm_kernel(const ushort* __restrict__ A, const ushort* __restrict__ Bt,
                            void* __restrict__ Cv, const float* __restrict__ bias,
                            int Mdim, int Ndim, int Kdim) {
    __shared__ __align__(16) ushort As[128 * 64];
    __shared__ __align__(16) ushort Bs[128 * 64];
    const int tid = threadIdx.x;
    const int lane = tid & 63;
    const int wv = tid >> 6;
    const int l4 = lane >> 4, l16 = lane & 15;
    const int nbn = Ndim >> 7;
    const int nwg = (Mdim >> 7) * nbn;
    int bid = blockIdx.x;
    bid = (bid & 7) * (nwg >> 3) + (bid >> 3);   // XCD swizzle (nwg % 8 == 0)
    const int bm = bid / nbn, bn = bid % nbn;
    const int wr = wv >> 1, wc = wv & 1;

    const ushort* Abase = A + (size_t)(bm * 128) * Kdim;
    const ushort* Bbase = Bt + (size_t)(bn * 128) * Kdim;

    v4f acc[4][4] = {};

    for (int k0 = 0; k0 < Kdim; k0 += 64) {
#pragma unroll
        for (int i = 0; i < 4; ++i) {
            const int c = i * 256 + tid;
            const int row = c >> 3;
            const int kc = (c & 7) ^ (row & 7);    // pre-swizzled global source
            gload16(Abase + (size_t)row * Kdim + k0 + kc * 8, &As[(i * 256 + wv * 64) * 8]);
        }
#pragma unroll
        for (int i = 0; i < 4; ++i) {
            const int c = i * 256 + tid;
            const int row = c >> 3;
            const int kc = (c & 7) ^ (row & 7);
            gload16(Bbase + (size_t)row * Kdim + k0 + kc * 8, &Bs[(i * 256 + wv * 64) * 8]);
        }
        __syncthreads();
#pragma unroll
        for (int kk = 0; kk < 2; ++kk) {
            v8bf af[4], bfr[4];
#pragma unroll
            for (int m = 0; m < 4; ++m) {
                const int r = wr * 64 + m * 16 + l16;
                const int slot = (kk * 4 + l4) ^ (r & 7);
                af[m] = *reinterpret_cast<const v8bf*>(&As[r * 64 + slot * 8]);
            }
#pragma unroll
            for (int n = 0; n < 4; ++n) {
                const int r = wc * 64 + n * 16 + l16;
                const int slot = (kk * 4 + l4) ^ (r & 7);
                bfr[n] = *reinterpret_cast<const v8bf*>(&Bs[r * 64 + slot * 8]);
            }
#pragma unroll
            for (int m = 0; m < 4; ++m)
#pragma unroll
                for (int n = 0; n < 4; ++n)
                    acc[m][n] = __builtin_amdgcn_mfma_f32_16x16x32_bf16(af[m], bfr[n], acc[m][n], 0, 0, 0);
        }
        __syncthreads();
    }

    const int r0 = bm * 128 + wr * 64 + l4 * 4;
    const int c0 = bn * 128 + wc * 64 + l16;
    if (OUTF32) {
        float* Cf = (float*)Cv;
#pragma unroll
        for (int n = 0; n < 4; ++n) {
            const float bv = bias[c0 + n * 16];
#pragma unroll
            for (int m = 0; m < 4; ++m)
#pragma unroll
                for (int j = 0; j < 4; ++j)
                    Cf[(size_t)(r0 + m * 16 + j) * Ndim + c0 + n * 16] = acc[m][n][j] + bv;
        }
    } else {
        ushort* Cb = (ushort*)Cv;
#pragma unroll
        for (int n = 0; n < 4; ++n)
#pragma unroll
            for (int m = 0; m < 4; ++m)
#pragma unroll
                for (int j = 0; j < 4; ++j)
                    Cb[(size_t)(r0 + m * 16 + j) * Ndim + c0 + n * 16] = f2bf(acc[m][n][j]);
    }
}

// ---------------- Flash attention v3 (causal, balanced split-row binning) ----------------
__global__ __launch_bounds__(256, 2) void flash_kernel(const ushort* __restrict__ qkv,
                                                       const ushort* __restrict__ vt,
                                                       ushort* __restrict__ ao) {
    __shared__ __align__(16) ushort Kl[2][64 * 128];   // [kv][d], 16B d-chunks XOR-swizzled
    __shared__ __align__(16) ushort Vl[2][128 * 64];   // [d][kv], 16B kv-chunks XOR-swizzled
    __shared__ __align__(16) ushort Pl[128 * 64];      // [slot][kv], XOR-swizzled

    const int xi = blockIdx.x;
    const int ti = (xi & 1) ? (xi >> 1) : (15 - (xi >> 1));  // heavy/light interleave
    const int h = blockIdx.y;
    const int b = blockIdx.z;
    const int tid = threadIdx.x;
    const int lane = tid & 63;
    const int wv = tid >> 6;
    const int l4 = lane >> 4, l16 = lane & 15;

    const int rbs[2]  = {ti * 64 + wv * 16, TDIM - 64 * (ti + 1) + wv * 16};  // block-local T rows
    const int diag[2] = {ti, 31 - ti};
    const int nkt = 32 - ti;

    // Q fragments, scale folded in (A-layout: row = lane&15, k = (lane>>4)*8 + ...)
    v8bf qf[2][4];
#pragma unroll
    for (int mg = 0; mg < 2; ++mg) {
        const ushort* qp = qkv + (size_t)(b * TDIM + rbs[mg] + l16) * E3 + h * HD + l4 * 8;
#pragma unroll
        for (int d0 = 0; d0 < 4; ++d0) {
            v8bf r = *reinterpret_cast<const v8bf*>(qp + d0 * 32);
            v8bf o;
#pragma unroll
            for (int e = 0; e < 8; ++e) {
                const float f = __uint_as_float(((uint32_t)(ushort)r[e]) << 16) * 0.08838834764831845f;
                o[e] = (short)f2bf(f);
            }
            qf[mg][d0] = o;
        }
    }

    float mrun[2][4], lrun[2][4];
#pragma unroll
    for (int mg = 0; mg < 2; ++mg)
#pragma unroll
        for (int j = 0; j < 4; ++j) { mrun[mg][j] = -1e30f; lrun[mg][j] = 0.0f; }
    v4f oacc[2][8] = {};

    const ushort* kbase = qkv + (size_t)(b * TDIM) * E3 + EDIM + h * HD;
    const ushort* vbase = vt + (size_t)((b * 16 + h) * HD) * TDIM;

#define STAGE(BUF, KT)                                                                        \
    do {                                                                                      \
        _Pragma("unroll") for (int i = 0; i < 4; ++i) {                                       \
            const int c = i * 256 + tid;                                                      \
            const int row = c >> 4;                                                           \
            const int dc = (c & 15) ^ (row & 7);                                              \
            gload16(kbase + (size_t)((KT) * 64 + row) * E3 + dc * 8,                          \
                    &Kl[BUF][(i * 256 + wv * 64) * 8]);                                       \
        }                                                                                     \
        _Pragma("unroll") for (int i = 0; i < 4; ++i) {                                       \
            const int c = i * 256 + tid;                                                      \
            const int row = c >> 3;                                                           \
            const int jc = (c & 7) ^ (row & 7);                                               \
            gload16(vbase + (size_t)row * TDIM + (KT) * 64 + jc * 8,                          \
                    &Vl[BUF][(i * 256 + wv * 64) * 8]);                                       \
        }                                                                                     \
    } while (0)

    STAGE(0, 0);
    __syncthreads();
    int cur = 0;

    for (int kt = 0; kt < nkt; ++kt) {
        if (kt + 1 < nkt) STAGE(cur ^ 1, kt + 1);   // prefetch overlaps compute

        const bool act0 = (kt <= diag[0]);          // mg0 active until its diagonal
        const ushort* Kb = &Kl[cur][0];
        const ushort* Vb = &Vl[cur][0];

        // ---- S = Q @ K^T ----
        v4f s[2][4] = {};
#pragma unroll
        for (int d0 = 0; d0 < 4; ++d0) {
            v8bf kf[4];
#pragma unroll
            for (int kvn = 0; kvn < 4; ++kvn) {
                const int r = kvn * 16 + l16;
                const int slot = (d0 * 4 + l4) ^ (r & 7);
                kf[kvn] = *reinterpret_cast<const v8bf*>(&Kb[r * 128 + slot * 8]);
            }
#pragma unroll
            for (int kvn = 0; kvn < 4; ++kvn) {
                if (act0)
                    s[0][kvn] = __builtin_amdgcn_mfma_f32_16x16x32_bf16(qf[0][d0], kf[kvn], s[0][kvn], 0, 0, 0);
                s[1][kvn] = __builtin_amdgcn_mfma_f32_16x16x32_bf16(qf[1][d0], kf[kvn], s[1][kvn], 0, 0, 0);
            }
        }

        // ---- per-group softmax + P write ----
#pragma unroll
        for (int mg = 0; mg < 2; ++mg) {
            if (mg == 0 && !act0) continue;

            float sv[4][4];
#pragma unroll
            for (int kvn = 0; kvn < 4; ++kvn)
#pragma unroll
                for (int j = 0; j < 4; ++j)
                    sv[kvn][j] = s[mg][kvn][j];

            if (kt == diag[mg]) {  // diagonal tile mask (block-local T coords)
                const int rg = rbs[mg] + l4 * 4;
#pragma unroll
                for (int kvn = 0; kvn < 4; ++kvn) {
                    const int cg = kt * 64 + kvn * 16 + l16;
#pragma unroll
                    for (int j = 0; j < 4; ++j)
                        if (cg > rg + j) sv[kvn][j] = -__builtin_inff();
                }
            }

            // row max (row spans the 16-lane group)
            float pm[4], dmax = -1e30f;
#pragma unroll
            for (int j = 0; j < 4; ++j) {
                float m0 = fmaxf(fmaxf(sv[0][j], sv[1][j]), fmaxf(sv[2][j], sv[3][j]));
                m0 = fmaxf(m0, __shfl_xor(m0, 1));
                m0 = fmaxf(m0, __shfl_xor(m0, 2));
                m0 = fmaxf(m0, __shfl_xor(m0, 4));
                m0 = fmaxf(m0, __shfl_xor(m0, 8));
                pm[j] = m0;
                dmax = fmaxf(dmax, m0 - mrun[mg][j]);
            }
            if (!__all(dmax <= 8.0f)) {   // T13 defer-max: rescale only when needed
                float corr[4];
#pragma unroll
                for (int j = 0; j < 4; ++j) {
                    const float mn = fmaxf(mrun[mg][j], pm[j]);
                    corr[j] = __expf(mrun[mg][j] - mn);
                    mrun[mg][j] = mn;
                    lrun[mg][j] *= corr[j];
                }
#pragma unroll
                for (int n = 0; n < 8; ++n)
#pragma unroll
                    for (int j = 0; j < 4; ++j)
                        oacc[mg][n][j] *= corr[j];
            }

            float p[4][4];
#pragma unroll
            for (int kvn = 0; kvn < 4; ++kvn)
#pragma unroll
                for (int j = 0; j < 4; ++j)
                    p[kvn][j] = __expf(sv[kvn][j] - mrun[mg][j]);
#pragma unroll
            for (int j = 0; j < 4; ++j)
                lrun[mg][j] += p[0][j] + p[1][j] + p[2][j] + p[3][j];

            // P -> LDS (swizzled), same-wave slots only
            const int row = wv * 32 + mg * 16 + l4 * 4;
#pragma unroll
            for (int kvn = 0; kvn < 4; ++kvn) {
                const int cc = kvn * 2 + (l16 >> 3);
#pragma unroll
                for (int j = 0; j < 4; ++j) {
                    const int r = row + j;
                    Pl[r * 64 + ((cc ^ (r & 7)) * 8) + (l16 & 7)] = f2bf(p[kvn][j]);
                }
            }
        }

        // ---- O += P @ V ----
#pragma unroll
        for (int kk = 0; kk < 2; ++kk) {
            v8bf pf[2];
#pragma unroll
            for (int mg = 0; mg < 2; ++mg) {
                if (mg == 0 && !act0) continue;
                const int r = wv * 32 + mg * 16 + l16;
                const int slot = (kk * 4 + l4) ^ (r & 7);
                pf[mg] = *reinterpret_cast<const v8bf*>(&Pl[r * 64 + slot * 8]);
            }
#pragma unroll
            for (int n = 0; n < 8; ++n) {
                const int dr = n * 16 + l16;
                const int slot = (kk * 4 + l4) ^ (dr & 7);
                v8bf vf = *reinterpret_cast<const v8bf*>(&Vb[dr * 64 + slot * 8]);
                if (act0)
                    oacc[0][n] = __builtin_amdgcn_mfma_f32_16x16x32_bf16(pf[0], vf, oacc[0][n], 0, 0, 0);
                oacc[1][n] = __builtin_amdgcn_mfma_f32_16x16x32_bf16(pf[1], vf, oacc[1][n], 0, 0, 0);
            }
        }
        __syncthreads();
        cur ^= 1;
    }
#undef STAGE

    // ---- epilogue: finish l reduction, normalize, store ----
#pragma unroll
    for (int mg = 0; mg < 2; ++mg) {
        float inv[4];
#pragma unroll
        for (int j = 0; j < 4; ++j) {
            float l = lrun[mg][j];
            l += __shfl_xor(l, 1);
            l += __shfl_xor(l, 2);
            l += __shfl_xor(l, 4);
            l += __shfl_xor(l, 8);
            inv[j] = 1.0f / l;
        }
        ushort* aop = ao + (size_t)(b * TDIM + rbs[mg] + l4 * 4) * EDIM + h * HD + l16;
#pragma unroll
        for (int n = 0; n < 8; ++n)
#pragma unroll
            for (int j = 0; j < 4; ++j)
                aop[(size_t)j * EDIM + n * 16] = f2bf(oacc[mg][n][j] * inv[j]);
    }
}

// ---------------- launcher ----------------
extern "C" void kernel_launch(void* const* d_in, const int* in_sizes, int n_in,
                              void* d_out, int out_size, void* d_ws, size_t ws_size,
                              hipStream_t stream) {
    (void)in_sizes; (void)n_in; (void)out_size; (void)ws_size;
    const float* x     = (const float*)d_in[0];
    const float* w_qkv = (const float*)d_in[1];
    const float* w_out = (const float*)d_in[2];
    const float* b_out = (const float*)d_in[3];

    uint8_t* ws = (uint8_t*)d_ws;
    ushort* qkv   = (ushort*)(ws);
    ushort* woutT = (ushort*)(ws + 50331648u);
    ushort* xb    = (ushort*)(ws + 58720256u);
    ushort* wqkvT = (ushort*)(ws + 75497472u);
    ushort* vtb   = xb;     // reuse after GEMM1 consumed xb
    ushort* ao    = wqkvT;  // reuse after GEMM1 consumed wqkvT

    cvtx_kernel<<<2048, 256, 0, stream>>>(x, xb, MROWS * EDIM);
    tcvt_kernel<<<dim3(E3 / 32, EDIM / 32), 256, 0, stream>>>(w_qkv, wqkvT, EDIM, E3);
    tcvt_kernel<<<dim3(EDIM / 32, EDIM / 32), 256, 0, stream>>>(w_out, woutT, EDIM, EDIM);

    gemm256_kernel<<<(MROWS / 256) * (E3 / 256), 512, 0, stream>>>(
        xb, wqkvT, qkv, MROWS, E3, EDIM);

    vtrans_kernel<<<dim3(TDIM / 32, HD / 32, BATCH * NH), 256, 0, stream>>>(qkv, vtb);

    flash_kernel<<<dim3(16, NH, BATCH), 256, 0, stream>>>(qkv, vtb, ao);

    gemm_kernel<1><<<(MROWS / 128) * (EDIM / 128), 256, 0, stream>>>(
        ao, woutT, d_out, b_out, MROWS, EDIM, EDIM);
}

// Round 5
// 276.687 us; speedup vs baseline: 1.0446x; 1.0446x over previous
//
#include <hip/hip_runtime.h>
#include <stdint.h>

// Problem constants
#define BATCH 2
#define TDIM 2048
#define EDIM 2048
#define NH 16
#define HD 128
#define E3 6144
#define MROWS 4096  // BATCH*TDIM

typedef short v8bf __attribute__((ext_vector_type(8)));   // 8 bf16 bit patterns (4 VGPRs)
typedef float v4f  __attribute__((ext_vector_type(4)));

typedef __attribute__((address_space(3))) uint8_t lds_u8;
typedef __attribute__((address_space(1))) uint8_t glb_u8;

__device__ __forceinline__ void gload16(const void* g, void* l) {
    __builtin_amdgcn_global_load_lds((const glb_u8*)g, (lds_u8*)l, 16, 0, 0);
}

__device__ __forceinline__ ushort f2bf(float f) {
    uint32_t u = __float_as_uint(f);
    return (ushort)((u + 0x7fffu + ((u >> 16) & 1u)) >> 16);  // RNE
}

// ---------------- fp32 -> bf16 elementwise ----------------
__global__ void cvtx_kernel(const float* __restrict__ in, ushort* __restrict__ out, int n) {
    int i = (blockIdx.x * 256 + threadIdx.x) * 4;
    const int stride = gridDim.x * 256 * 4;
    for (; i < n; i += stride) {
        const float4 v = *reinterpret_cast<const float4*>(in + i);
        ushort4 o = make_ushort4(f2bf(v.x), f2bf(v.y), f2bf(v.z), f2bf(v.w));
        *reinterpret_cast<ushort4*>(out + i) = o;
    }
}

// ---------------- fp32 [R][C] -> bf16 [C][R] (transpose + convert) ----------------
__global__ void tcvt_kernel(const float* __restrict__ in, ushort* __restrict__ out, int R, int C) {
    __shared__ float t[32][33];
    const int tc = blockIdx.x * 32;
    const int tr = blockIdx.y * 32;
    const int tid = threadIdx.x;
    const int row = tid >> 3, c4 = (tid & 7) * 4;
    const float4 v = *reinterpret_cast<const float4*>(in + (size_t)(tr + row) * C + tc + c4);
    t[row][c4] = v.x; t[row][c4 + 1] = v.y; t[row][c4 + 2] = v.z; t[row][c4 + 3] = v.w;
    __syncthreads();
    const int oc = tid >> 3, r4 = (tid & 7) * 4;
    ushort4 o = make_ushort4(f2bf(t[r4][oc]), f2bf(t[r4 + 1][oc]),
                             f2bf(t[r4 + 2][oc]), f2bf(t[r4 + 3][oc]));
    *reinterpret_cast<ushort4*>(out + (size_t)(tc + oc) * R + tr + r4) = o;
}

// ---------------- V extract + transpose: qkv[.][4096+h*128+d] -> vt[bh][d][t] ----------------
__global__ void vtrans_kernel(const ushort* __restrict__ qkv, ushort* __restrict__ vt) {
    __shared__ ushort t[32][33];
    const int bh = blockIdx.z;
    const int b = bh >> 4, h = bh & 15;
    const int tr = blockIdx.x * 32;   // t tile
    const int tc = blockIdx.y * 32;   // d tile
    const int tid = threadIdx.x;
    const int row = tid >> 3, c4 = (tid & 7) * 4;
    const ushort4 v = *reinterpret_cast<const ushort4*>(
        qkv + (size_t)(b * TDIM + tr + row) * E3 + 2 * EDIM + h * HD + tc + c4);
    t[row][c4] = v.x; t[row][c4 + 1] = v.y; t[row][c4 + 2] = v.z; t[row][c4 + 3] = v.w;
    __syncthreads();
    const int oc = tid >> 3, r4 = (tid & 7) * 4;
    ushort4 o = make_ushort4(t[r4][oc], t[r4 + 1][oc], t[r4 + 2][oc], t[r4 + 3][oc]);
    *reinterpret_cast<ushort4*>(vt + (size_t)(bh * HD + tc + oc) * TDIM + tr + r4) = o;
}

// ---------------- GEMM1: 128x256 tile, BK=64, 8 waves, phase-interleaved counted-vmcnt ----
// C[M][N] (bf16) = A[M][K] * Bt[N][K]^T. M%128==0, N%256==0, K%64==0, NT>=3, nwg%8==0.
// A-half-major / B-half-major lane maps: halves retire collectively per phase, so staging
// of tile t+2 interleaves into the current buffer's retired regions (T3+T4).
__global__ __launch_bounds__(512, 2) void gemm8p_kernel(const ushort* __restrict__ A,
                                                        const ushort* __restrict__ Bt,
                                                        ushort* __restrict__ C,
                                                        int Mdim, int Ndim, int Kdim) {
    __shared__ __align__(16) ushort AL[2][128 * 64];   // 16 KiB per buf
    __shared__ __align__(16) ushort BL[2][256 * 64];   // 32 KiB per buf; total 96 KiB
    const int tid = threadIdx.x;
    const int lane = tid & 63;
    const int wv = tid >> 6;              // 0..7
    const int l4 = lane >> 4, l16 = lane & 15;
    const int wr = wv >> 2, wc = wv & 3;  // wave tile 64x64: M-half x 4 N-quarters (per half)
    const int nbn = Ndim >> 8;
    const int nwg = (Mdim >> 7) * nbn;
    int bid = blockIdx.x;
    bid = (bid & 7) * (nwg >> 3) + (bid >> 3);   // XCD swizzle (nwg % 8 == 0)
    const int bm = bid / nbn, bn = bid % nbn;

    const ushort* Abase = A + (size_t)(bm * 128) * Kdim;
    const ushort* Bbase = Bt + (size_t)(bn * 256) * Kdim;
    const int NT = Kdim >> 6;

    const int arow = tid >> 3;                 // 0..63
    const int akc = (tid & 7) ^ (arow & 7);    // pre-swizzled global chunk

    // A unit (64 rows, 8KB) = 1 gload16/thread; B unit (128 rows, 16KB) = 2.
#define STAGE_A(BUF, T, H)                                                                   \
    gload16(Abase + (size_t)((H) * 64 + arow) * Kdim + (T) * 64 + akc * 8,                   \
            &AL[BUF][((H) * 512 + wv * 64) * 8])
#define STAGE_B(BUF, T, H)                                                                   \
    do {                                                                                     \
        gload16(Bbase + (size_t)((H) * 128 + arow) * Kdim + (T) * 64 + akc * 8,              \
                &BL[BUF][((H) * 1024 + wv * 64) * 8]);                                       \
        gload16(Bbase + (size_t)((H) * 128 + 64 + arow) * Kdim + (T) * 64 + akc * 8,         \
                &BL[BUF][((H) * 1024 + 512 + wv * 64) * 8]);                                 \
    } while (0)

    // Prologue: tile0 fully (6 loads) + tile1 minus Ah1 (5 loads).
    STAGE_A(0, 0, 0); STAGE_A(0, 0, 1); STAGE_B(0, 0, 0); STAGE_B(0, 0, 1);
    STAGE_A(1, 1, 0); STAGE_B(1, 1, 0); STAGE_B(1, 1, 1);
    asm volatile("s_waitcnt vmcnt(5)" ::: "memory");   // tile0 resident; tile1's 5 in flight
    __builtin_amdgcn_s_barrier();

    v4f acc[2][2][2][2] = {};   // [mh][nh][m][n]

    for (int t = 0; t < NT; ++t) {
        const int cur = t & 1;
        const ushort* As = &AL[cur][0];
        const ushort* Bs = &BL[cur][0];
        v8bf af[2][2], bfr[2][2][2];

        // ---- phase 1: mh=0 quadrant pair ----
#pragma unroll
        for (int m = 0; m < 2; ++m)
#pragma unroll
            for (int kk = 0; kk < 2; ++kk) {
                const int rA = wr * 32 + m * 16 + l16;
                const int slot = (kk * 4 + l4) ^ (l16 & 7);
                af[m][kk] = *reinterpret_cast<const v8bf*>(&As[rA * 64 + slot * 8]);
            }
#pragma unroll
        for (int nh = 0; nh < 2; ++nh)
#pragma unroll
            for (int n = 0; n < 2; ++n)
#pragma unroll
                for (int kk = 0; kk < 2; ++kk) {
                    const int rB = nh * 128 + wc * 32 + n * 16 + l16;
                    const int slot = (kk * 4 + l4) ^ (l16 & 7);
                    bfr[nh][n][kk] = *reinterpret_cast<const v8bf*>(&Bs[rB * 64 + slot * 8]);
                }
        if (t + 1 < NT) STAGE_A(cur ^ 1, t + 1, 1);   // completes tile t+1 (safe: other buf)
        __builtin_amdgcn_s_barrier();
        __builtin_amdgcn_s_setprio(1);
#pragma unroll
        for (int kk = 0; kk < 2; ++kk)
#pragma unroll
            for (int m = 0; m < 2; ++m)
#pragma unroll
                for (int nh = 0; nh < 2; ++nh)
#pragma unroll
                    for (int n = 0; n < 2; ++n)
                        acc[0][nh][m][n] = __builtin_amdgcn_mfma_f32_16x16x32_bf16(
                            af[m][kk], bfr[nh][n][kk], acc[0][nh][m][n], 0, 0, 0);
        __builtin_amdgcn_s_setprio(0);
        __builtin_amdgcn_s_barrier();

        // ---- phase 2: mh=1 (B frags reused from registers) ----
#pragma unroll
        for (int m = 0; m < 2; ++m)
#pragma unroll
            for (int kk = 0; kk < 2; ++kk) {
                const int rA = 64 + wr * 32 + m * 16 + l16;
                const int slot = (kk * 4 + l4) ^ (l16 & 7);
                af[m][kk] = *reinterpret_cast<const v8bf*>(&As[rA * 64 + slot * 8]);
            }
        if (t + 2 < NT) {   // stage into retired regions of current buffer
            STAGE_A(cur, t + 2, 0);
            STAGE_B(cur, t + 2, 0);
            STAGE_B(cur, t + 2, 1);
        }
        __builtin_amdgcn_s_barrier();
        __builtin_amdgcn_s_setprio(1);
#pragma unroll
        for (int kk = 0; kk < 2; ++kk)
#pragma unroll
            for (int m = 0; m < 2; ++m)
#pragma unroll
                for (int nh = 0; nh < 2; ++nh)
#pragma unroll
                    for (int n = 0; n < 2; ++n)
                        acc[1][nh][m][n] = __builtin_amdgcn_mfma_f32_16x16x32_bf16(
                            af[m][kk], bfr[nh][n][kk], acc[1][nh][m][n], 0, 0, 0);
        __builtin_amdgcn_s_setprio(0);
        if (t + 2 < NT)
            asm volatile("s_waitcnt vmcnt(5)" ::: "memory");   // tile t+1 fully resident
        else if (t + 1 < NT)
            asm volatile("s_waitcnt vmcnt(0)" ::: "memory");   // drain last tile's loads
        __builtin_amdgcn_s_barrier();
    }
#undef STAGE_A
#undef STAGE_B

    // Epilogue. C/D layout: col = lane&15, row = (lane>>4)*4 + j
#pragma unroll
    for (int mh = 0; mh < 2; ++mh)
#pragma unroll
        for (int m = 0; m < 2; ++m)
#pragma unroll
            for (int nh = 0; nh < 2; ++nh)
#pragma unroll
                for (int n = 0; n < 2; ++n) {
                    const int r0 = bm * 128 + mh * 64 + wr * 32 + m * 16 + l4 * 4;
                    const int c0 = bn * 256 + nh * 128 + wc * 32 + n * 16 + l16;
#pragma unroll
                    for (int j = 0; j < 4; ++j)
                        C[(size_t)(r0 + j) * Ndim + c0] = f2bf(acc[mh][nh][m][n][j]);
                }
}

// ---------------- bf16 GEMM (128x128, m97-structure) -- GEMM2 (f32 out + bias) ----------------
template <int OUTF32>
__global__ void gemm_kernel(const ushort* __restrict__ A, const ushort* __restrict__ Bt,
                            void* __restrict__ Cv, const float* __restrict__ bias,
                            int Mdim, int Ndim, int Kdim) {
    __shared__ __align__(16) ushort As[128 * 64];
    __shared__ __align__(16) ushort Bs[128 * 64];
    const int tid = threadIdx.x;
    const int lane = tid & 63;
    const int wv = tid >> 6;
    const int l4 = lane >> 4, l16 = lane & 15;
    const int nbn = Ndim >> 7;
    const int nwg = (Mdim >> 7) * nbn;
    int bid = blockIdx.x;
    bid = (bid & 7) * (nwg >> 3) + (bid >> 3);   // XCD swizzle (nwg % 8 == 0)
    const int bm = bid / nbn, bn = bid % nbn;
    const int wr = wv >> 1, wc = wv & 1;

    const ushort* Abase = A + (size_t)(bm * 128) * Kdim;
    const ushort* Bbase = Bt + (size_t)(bn * 128) * Kdim;

    v4f acc[4][4] = {};

    for (int k0 = 0; k0 < Kdim; k0 += 64) {
#pragma unroll
        for (int i = 0; i < 4; ++i) {
            const int c = i * 256 + tid;
            const int row = c >> 3;
            const int kc = (c & 7) ^ (row & 7);    // pre-swizzled global source
            gload16(Abase + (size_t)row * Kdim + k0 + kc * 8, &As[(i * 256 + wv * 64) * 8]);
        }
#pragma unroll
        for (int i = 0; i < 4; ++i) {
            const int c = i * 256 + tid;
            const int row = c >> 3;
            const int kc = (c & 7) ^ (row & 7);
            gload16(Bbase + (size_t)row * Kdim + k0 + kc * 8, &Bs[(i * 256 + wv * 64) * 8]);
        }
        __syncthreads();
#pragma unroll
        for (int kk = 0; kk < 2; ++kk) {
            v8bf af[4], bfr[4];
#pragma unroll
            for (int m = 0; m < 4; ++m) {
                const int r = wr * 64 + m * 16 + l16;
                const int slot = (kk * 4 + l4) ^ (r & 7);
                af[m] = *reinterpret_cast<const v8bf*>(&As[r * 64 + slot * 8]);
            }
#pragma unroll
            for (int n = 0; n < 4; ++n) {
                const int r = wc * 64 + n * 16 + l16;
                const int slot = (kk * 4 + l4) ^ (r & 7);
                bfr[n] = *reinterpret_cast<const v8bf*>(&Bs[r * 64 + slot * 8]);
            }
#pragma unroll
            for (int m = 0; m < 4; ++m)
#pragma unroll
                for (int n = 0; n < 4; ++n)
                    acc[m][n] = __builtin_amdgcn_mfma_f32_16x16x32_bf16(af[m], bfr[n], acc[m][n], 0, 0, 0);
        }
        __syncthreads();
    }

    const int r0 = bm * 128 + wr * 64 + l4 * 4;
    const int c0 = bn * 128 + wc * 64 + l16;
    if (OUTF32) {
        float* Cf = (float*)Cv;
#pragma unroll
        for (int n = 0; n < 4; ++n) {
            const float bv = bias[c0 + n * 16];
#pragma unroll
            for (int m = 0; m < 4; ++m)
#pragma unroll
                for (int j = 0; j < 4; ++j)
                    Cf[(size_t)(r0 + m * 16 + j) * Ndim + c0 + n * 16] = acc[m][n][j] + bv;
        }
    } else {
        ushort* Cb = (ushort*)Cv;
#pragma unroll
        for (int n = 0; n < 4; ++n)
#pragma unroll
            for (int m = 0; m < 4; ++m)
#pragma unroll
                for (int j = 0; j < 4; ++j)
                    Cb[(size_t)(r0 + m * 16 + j) * Ndim + c0 + n * 16] = f2bf(acc[m][n][j]);
    }
}

// ---------------- Flash attention v3 (causal, balanced split-row binning) ----------------
__global__ __launch_bounds__(256, 2) void flash_kernel(const ushort* __restrict__ qkv,
                                                       const ushort* __restrict__ vt,
                                                       ushort* __restrict__ ao) {
    __shared__ __align__(16) ushort Kl[2][64 * 128];   // [kv][d], 16B d-chunks XOR-swizzled
    __shared__ __align__(16) ushort Vl[2][128 * 64];   // [d][kv], 16B kv-chunks XOR-swizzled
    __shared__ __align__(16) ushort Pl[128 * 64];      // [slot][kv], XOR-swizzled

    const int xi = blockIdx.x;
    const int ti = (xi & 1) ? (xi >> 1) : (15 - (xi >> 1));  // heavy/light interleave
    const int h = blockIdx.y;
    const int b = blockIdx.z;
    const int tid = threadIdx.x;
    const int lane = tid & 63;
    const int wv = tid >> 6;
    const int l4 = lane >> 4, l16 = lane & 15;

    const int rbs[2]  = {ti * 64 + wv * 16, TDIM - 64 * (ti + 1) + wv * 16};  // block-local T rows
    const int diag[2] = {ti, 31 - ti};
    const int nkt = 32 - ti;

    // Q fragments, scale folded in (A-layout: row = lane&15, k = (lane>>4)*8 + ...)
    v8bf qf[2][4];
#pragma unroll
    for (int mg = 0; mg < 2; ++mg) {
        const ushort* qp = qkv + (size_t)(b * TDIM + rbs[mg] + l16) * E3 + h * HD + l4 * 8;
#pragma unroll
        for (int d0 = 0; d0 < 4; ++d0) {
            v8bf r = *reinterpret_cast<const v8bf*>(qp + d0 * 32);
            v8bf o;
#pragma unroll
            for (int e = 0; e < 8; ++e) {
                const float f = __uint_as_float(((uint32_t)(ushort)r[e]) << 16) * 0.08838834764831845f;
                o[e] = (short)f2bf(f);
            }
            qf[mg][d0] = o;
        }
    }

    float mrun[2][4], lrun[2][4];
#pragma unroll
    for (int mg = 0; mg < 2; ++mg)
#pragma unroll
        for (int j = 0; j < 4; ++j) { mrun[mg][j] = -1e30f; lrun[mg][j] = 0.0f; }
    v4f oacc[2][8] = {};

    const ushort* kbase = qkv + (size_t)(b * TDIM) * E3 + EDIM + h * HD;
    const ushort* vbase = vt + (size_t)((b * 16 + h) * HD) * TDIM;

#define STAGE(BUF, KT)                                                                        \
    do {                                                                                      \
        _Pragma("unroll") for (int i = 0; i < 4; ++i) {                                       \
            const int c = i * 256 + tid;                                                      \
            const int row = c >> 4;                                                           \
            const int dc = (c & 15) ^ (row & 7);                                              \
            gload16(kbase + (size_t)((KT) * 64 + row) * E3 + dc * 8,                          \
                    &Kl[BUF][(i * 256 + wv * 64) * 8]);                                       \
        }                                                                                     \
        _Pragma("unroll") for (int i = 0; i < 4; ++i) {                                       \
            const int c = i * 256 + tid;                                                      \
            const int row = c >> 3;                                                           \
            const int jc = (c & 7) ^ (row & 7);                                               \
            gload16(vbase + (size_t)row * TDIM + (KT) * 64 + jc * 8,                          \
                    &Vl[BUF][(i * 256 + wv * 64) * 8]);                                       \
        }                                                                                     \
    } while (0)

    STAGE(0, 0);
    __syncthreads();
    int cur = 0;

    for (int kt = 0; kt < nkt; ++kt) {
        if (kt + 1 < nkt) STAGE(cur ^ 1, kt + 1);   // prefetch overlaps compute

        const bool act0 = (kt <= diag[0]);          // mg0 active until its diagonal
        const ushort* Kb = &Kl[cur][0];
        const ushort* Vb = &Vl[cur][0];

        // ---- S = Q @ K^T ----
        v4f s[2][4] = {};
#pragma unroll
        for (int d0 = 0; d0 < 4; ++d0) {
            v8bf kf[4];
#pragma unroll
            for (int kvn = 0; kvn < 4; ++kvn) {
                const int r = kvn * 16 + l16;
                const int slot = (d0 * 4 + l4) ^ (r & 7);
                kf[kvn] = *reinterpret_cast<const v8bf*>(&Kb[r * 128 + slot * 8]);
            }
#pragma unroll
            for (int kvn = 0; kvn < 4; ++kvn) {
                if (act0)
                    s[0][kvn] = __builtin_amdgcn_mfma_f32_16x16x32_bf16(qf[0][d0], kf[kvn], s[0][kvn], 0, 0, 0);
                s[1][kvn] = __builtin_amdgcn_mfma_f32_16x16x32_bf16(qf[1][d0], kf[kvn], s[1][kvn], 0, 0, 0);
            }
        }

        // ---- per-group softmax + P write ----
#pragma unroll
        for (int mg = 0; mg < 2; ++mg) {
            if (mg == 0 && !act0) continue;

            float sv[4][4];
#pragma unroll
            for (int kvn = 0; kvn < 4; ++kvn)
#pragma unroll
                for (int j = 0; j < 4; ++j)
                    sv[kvn][j] = s[mg][kvn][j];

            if (kt == diag[mg]) {  // diagonal tile mask (block-local T coords)
                const int rg = rbs[mg] + l4 * 4;
#pragma unroll
                for (int kvn = 0; kvn < 4; ++kvn) {
                    const int cg = kt * 64 + kvn * 16 + l16;
#pragma unroll
                    for (int j = 0; j < 4; ++j)
                        if (cg > rg + j) sv[kvn][j] = -__builtin_inff();
                }
            }

            // row max (row spans the 16-lane group)
            float pm[4], dmax = -1e30f;
#pragma unroll
            for (int j = 0; j < 4; ++j) {
                float m0 = fmaxf(fmaxf(sv[0][j], sv[1][j]), fmaxf(sv[2][j], sv[3][j]));
                m0 = fmaxf(m0, __shfl_xor(m0, 1));
                m0 = fmaxf(m0, __shfl_xor(m0, 2));
                m0 = fmaxf(m0, __shfl_xor(m0, 4));
                m0 = fmaxf(m0, __shfl_xor(m0, 8));
                pm[j] = m0;
                dmax = fmaxf(dmax, m0 - mrun[mg][j]);
            }
            if (!__all(dmax <= 8.0f)) {   // T13 defer-max: rescale only when needed
                float corr[4];
#pragma unroll
                for (int j = 0; j < 4; ++j) {
                    const float mn = fmaxf(mrun[mg][j], pm[j]);
                    corr[j] = __expf(mrun[mg][j] - mn);
                    mrun[mg][j] = mn;
                    lrun[mg][j] *= corr[j];
                }
#pragma unroll
                for (int n = 0; n < 8; ++n)
#pragma unroll
                    for (int j = 0; j < 4; ++j)
                        oacc[mg][n][j] *= corr[j];
            }

            float p[4][4];
#pragma unroll
            for (int kvn = 0; kvn < 4; ++kvn)
#pragma unroll
                for (int j = 0; j < 4; ++j)
                    p[kvn][j] = __expf(sv[kvn][j] - mrun[mg][j]);
#pragma unroll
            for (int j = 0; j < 4; ++j)
                lrun[mg][j] += p[0][j] + p[1][j] + p[2][j] + p[3][j];

            // P -> LDS (swizzled), same-wave slots only
            const int row = wv * 32 + mg * 16 + l4 * 4;
#pragma unroll
            for (int kvn = 0; kvn < 4; ++kvn) {
                const int cc = kvn * 2 + (l16 >> 3);
#pragma unroll
                for (int j = 0; j < 4; ++j) {
                    const int r = row + j;
                    Pl[r * 64 + ((cc ^ (r & 7)) * 8) + (l16 & 7)] = f2bf(p[kvn][j]);
                }
            }
        }

        // ---- O += P @ V ----
#pragma unroll
        for (int kk = 0; kk < 2; ++kk) {
            v8bf pf[2];
#pragma unroll
            for (int mg = 0; mg < 2; ++mg) {
                if (mg == 0 && !act0) continue;
                const int r = wv * 32 + mg * 16 + l16;
                const int slot = (kk * 4 + l4) ^ (r & 7);
                pf[mg] = *reinterpret_cast<const v8bf*>(&Pl[r * 64 + slot * 8]);
            }
#pragma unroll
            for (int n = 0; n < 8; ++n) {
                const int dr = n * 16 + l16;
                const int slot = (kk * 4 + l4) ^ (dr & 7);
                v8bf vf = *reinterpret_cast<const v8bf*>(&Vb[dr * 64 + slot * 8]);
                if (act0)
                    oacc[0][n] = __builtin_amdgcn_mfma_f32_16x16x32_bf16(pf[0], vf, oacc[0][n], 0, 0, 0);
                oacc[1][n] = __builtin_amdgcn_mfma_f32_16x16x32_bf16(pf[1], vf, oacc[1][n], 0, 0, 0);
            }
        }
        __syncthreads();
        cur ^= 1;
    }
#undef STAGE

    // ---- epilogue: finish l reduction, normalize, store ----
#pragma unroll
    for (int mg = 0; mg < 2; ++mg) {
        float inv[4];
#pragma unroll
        for (int j = 0; j < 4; ++j) {
            float l = lrun[mg][j];
            l += __shfl_xor(l, 1);
            l += __shfl_xor(l, 2);
            l += __shfl_xor(l, 4);
            l += __shfl_xor(l, 8);
            inv[j] = 1.0f / l;
        }
        ushort* aop = ao + (size_t)(b * TDIM + rbs[mg] + l4 * 4) * EDIM + h * HD + l16;
#pragma unroll
        for (int n = 0; n < 8; ++n)
#pragma unroll
            for (int j = 0; j < 4; ++j)
                aop[(size_t)j * EDIM + n * 16] = f2bf(oacc[mg][n][j] * inv[j]);
    }
}

// ---------------- launcher ----------------
extern "C" void kernel_launch(void* const* d_in, const int* in_sizes, int n_in,
                              void* d_out, int out_size, void* d_ws, size_t ws_size,
                              hipStream_t stream) {
    (void)in_sizes; (void)n_in; (void)out_size; (void)ws_size;
    const float* x     = (const float*)d_in[0];
    const float* w_qkv = (const float*)d_in[1];
    const float* w_out = (const float*)d_in[2];
    const float* b_out = (const float*)d_in[3];

    uint8_t* ws = (uint8_t*)d_ws;
    ushort* qkv   = (ushort*)(ws);
    ushort* woutT = (ushort*)(ws + 50331648u);
    ushort* xb    = (ushort*)(ws + 58720256u);
    ushort* wqkvT = (ushort*)(ws + 75497472u);
    ushort* vtb   = xb;     // reuse after GEMM1 consumed xb
    ushort* ao    = wqkvT;  // reuse after GEMM1 consumed wqkvT

    cvtx_kernel<<<2048, 256, 0, stream>>>(x, xb, MROWS * EDIM);
    tcvt_kernel<<<dim3(E3 / 32, EDIM / 32), 256, 0, stream>>>(w_qkv, wqkvT, EDIM, E3);
    tcvt_kernel<<<dim3(EDIM / 32, EDIM / 32), 256, 0, stream>>>(w_out, woutT, EDIM, EDIM);

    gemm8p_kernel<<<(MROWS / 128) * (E3 / 256), 512, 0, stream>>>(
        xb, wqkvT, qkv, MROWS, E3, EDIM);

    vtrans_kernel<<<dim3(TDIM / 32, HD / 32, BATCH * NH), 256, 0, stream>>>(qkv, vtb);

    flash_kernel<<<dim3(16, NH, BATCH), 256, 0, stream>>>(qkv, vtb, ao);

    gemm_kernel<1><<<(MROWS / 128) * (EDIM / 128), 256, 0, stream>>>(
        ao, woutT, d_out, b_out, MROWS, EDIM, EDIM);
}

// Round 6
// 274.987 us; speedup vs baseline: 1.0511x; 1.0062x over previous
//
#include <hip/hip_runtime.h>
#include <stdint.h>

// Problem constants
#define BATCH 2
#define TDIM 2048
#define EDIM 2048
#define NH 16
#define HD 128
#define E3 6144
#define MROWS 4096  // BATCH*TDIM

typedef short v8bf __attribute__((ext_vector_type(8)));   // 8 bf16 bit patterns (4 VGPRs)
typedef float v4f  __attribute__((ext_vector_type(4)));

typedef __attribute__((address_space(3))) uint8_t lds_u8;
typedef __attribute__((address_space(1))) uint8_t glb_u8;

__device__ __forceinline__ void gload16(const void* g, void* l) {
    __builtin_amdgcn_global_load_lds((const glb_u8*)g, (lds_u8*)l, 16, 0, 0);
}

__device__ __forceinline__ ushort f2bf(float f) {
    uint32_t u = __float_as_uint(f);
    return (ushort)((u + 0x7fffu + ((u >> 16) & 1u)) >> 16);  // RNE
}

// ---------------- fp32 -> bf16 elementwise ----------------
__global__ void cvtx_kernel(const float* __restrict__ in, ushort* __restrict__ out, int n) {
    int i = (blockIdx.x * 256 + threadIdx.x) * 4;
    const int stride = gridDim.x * 256 * 4;
    for (; i < n; i += stride) {
        const float4 v = *reinterpret_cast<const float4*>(in + i);
        ushort4 o = make_ushort4(f2bf(v.x), f2bf(v.y), f2bf(v.z), f2bf(v.w));
        *reinterpret_cast<ushort4*>(out + i) = o;
    }
}

// ---------------- fp32 [R][C] -> bf16 [C][R] (transpose + convert) ----------------
__global__ void tcvt_kernel(const float* __restrict__ in, ushort* __restrict__ out, int R, int C) {
    __shared__ float t[32][33];
    const int tc = blockIdx.x * 32;
    const int tr = blockIdx.y * 32;
    const int tid = threadIdx.x;
    const int row = tid >> 3, c4 = (tid & 7) * 4;
    const float4 v = *reinterpret_cast<const float4*>(in + (size_t)(tr + row) * C + tc + c4);
    t[row][c4] = v.x; t[row][c4 + 1] = v.y; t[row][c4 + 2] = v.z; t[row][c4 + 3] = v.w;
    __syncthreads();
    const int oc = tid >> 3, r4 = (tid & 7) * 4;
    ushort4 o = make_ushort4(f2bf(t[r4][oc]), f2bf(t[r4 + 1][oc]),
                             f2bf(t[r4 + 2][oc]), f2bf(t[r4 + 3][oc]));
    *reinterpret_cast<ushort4*>(out + (size_t)(tc + oc) * R + tr + r4) = o;
}

// ---------------- V extract + transpose: qkv[.][4096+h*128+d] -> vt[bh][d][t] ----------------
__global__ void vtrans_kernel(const ushort* __restrict__ qkv, ushort* __restrict__ vt) {
    __shared__ ushort t[32][33];
    const int bh = blockIdx.z;
    const int b = bh >> 4, h = bh & 15;
    const int tr = blockIdx.x * 32;   // t tile
    const int tc = blockIdx.y * 32;   // d tile
    const int tid = threadIdx.x;
    const int row = tid >> 3, c4 = (tid & 7) * 4;
    const ushort4 v = *reinterpret_cast<const ushort4*>(
        qkv + (size_t)(b * TDIM + tr + row) * E3 + 2 * EDIM + h * HD + tc + c4);
    t[row][c4] = v.x; t[row][c4 + 1] = v.y; t[row][c4 + 2] = v.z; t[row][c4 + 3] = v.w;
    __syncthreads();
    const int oc = tid >> 3, r4 = (tid & 7) * 4;
    ushort4 o = make_ushort4(t[r4][oc], t[r4 + 1][oc], t[r4 + 2][oc], t[r4 + 3][oc]);
    *reinterpret_cast<ushort4*>(vt + (size_t)(bh * HD + tc + oc) * TDIM + tr + r4) = o;
}

// ---------------- GEMM: 128x256 tile, BK=64, 8 waves, faithful phase template ----------------
// C[M][N] = A[M][K] * Bt[N][K]^T (+bias if OUTF32). M%128==0, N%256==0, K%64==0, NT>=4, nwg%8==0.
// Per K-tile: 2 phases {ds_read ∥ stage-chunk -> barrier -> lgkmcnt(0) -> 16 MFMA -> vmcnt(6) -> barrier}.
// chunk0={A,B0,B1} (4 gloads, used in phase alpha), chunk1={B2,B3} (2 gloads, used in phase beta),
// staggered 2 K-tiles ahead into dead LDS regions. Steady outstanding: 6->8->6->10->6.
template <int OUTF32>
__global__ __launch_bounds__(512, 2) void gemm2p_kernel(const ushort* __restrict__ A,
                                                        const ushort* __restrict__ Bt,
                                                        void* __restrict__ Cv,
                                                        const float* __restrict__ bias,
                                                        int Mdim, int Ndim, int Kdim) {
    __shared__ __align__(16) ushort AL[2][128 * 64];   // 16 KiB per buf
    __shared__ __align__(16) ushort BL[2][256 * 64];   // 32 KiB per buf; total 96 KiB
    const int tid = threadIdx.x;
    const int lane = tid & 63;
    const int wv = tid >> 6;              // 0..7
    const int l4 = lane >> 4, l16 = lane & 15;
    const int wr = wv >> 2, wc = wv & 3;  // wave tile 64x64 (rows wr*64.., cols: two 32-strips)
    const int nbn = Ndim >> 8;
    const int nwg = (Mdim >> 7) * nbn;
    int bid = blockIdx.x;
    bid = (bid & 7) * (nwg >> 3) + (bid >> 3);   // XCD swizzle (nwg % 8 == 0)
    const int bm = bid / nbn, bn = bid % nbn;

    const ushort* Abase = A + (size_t)(bm * 128) * Kdim;
    const ushort* Bbase = Bt + (size_t)(bn * 256) * Kdim;
    const int NT = Kdim >> 6;

    const int arow = tid >> 3;                 // 0..63 (row within a 64-row unit)
    const int akc = (tid & 7) ^ (arow & 7);    // pre-swizzled global 16B-chunk

    // chunk0: A rows 0-127 + B rows 0-127 (4 gloads). chunk1: B rows 128-255 (2 gloads).
#define CHUNK0(BUF, T)                                                                       \
    do {                                                                                     \
        gload16(Abase + (size_t)arow * Kdim + (T) * 64 + akc * 8,                            \
                &AL[BUF][(wv * 64) * 8]);                                                    \
        gload16(Abase + (size_t)(64 + arow) * Kdim + (T) * 64 + akc * 8,                     \
                &AL[BUF][(512 + wv * 64) * 8]);                                              \
        gload16(Bbase + (size_t)arow * Kdim + (T) * 64 + akc * 8,                            \
                &BL[BUF][(wv * 64) * 8]);                                                    \
        gload16(Bbase + (size_t)(64 + arow) * Kdim + (T) * 64 + akc * 8,                     \
                &BL[BUF][(512 + wv * 64) * 8]);                                              \
    } while (0)
#define CHUNK1(BUF, T)                                                                       \
    do {                                                                                     \
        gload16(Bbase + (size_t)(128 + arow) * Kdim + (T) * 64 + akc * 8,                    \
                &BL[BUF][(1024 + wv * 64) * 8]);                                             \
        gload16(Bbase + (size_t)(192 + arow) * Kdim + (T) * 64 + akc * 8,                    \
                &BL[BUF][(1536 + wv * 64) * 8]);                                             \
    } while (0)

    // Prologue: c0(0), c1(0), c0(1) -> wait for tile0 resident (c0(1)'s 4 stay in flight).
    CHUNK0(0, 0);
    CHUNK1(0, 0);
    CHUNK0(1, 1);
    asm volatile("s_waitcnt vmcnt(4)" ::: "memory");
    __builtin_amdgcn_s_barrier();
    __builtin_amdgcn_sched_barrier(0);

    v4f acc[2][4][2] = {};   // [nh][m][n]

    for (int t = 0; t < NT; ++t) {
        const int cur = t & 1;
        const ushort* As = &AL[cur][0];
        const ushort* Bs = &BL[cur][0];
        v8bf af[4][2], bfr[2][2];

        // ======== phase alpha: nh=0 (A + B rows 0-127) ========
#pragma unroll
        for (int m = 0; m < 4; ++m)
#pragma unroll
            for (int kk = 0; kk < 2; ++kk) {
                const int r = wr * 64 + m * 16 + l16;
                const int slot = (kk * 4 + l4) ^ (l16 & 7);
                af[m][kk] = *reinterpret_cast<const v8bf*>(&As[r * 64 + slot * 8]);
            }
#pragma unroll
        for (int n = 0; n < 2; ++n)
#pragma unroll
            for (int kk = 0; kk < 2; ++kk) {
                const int r = wc * 32 + n * 16 + l16;
                const int slot = (kk * 4 + l4) ^ (l16 & 7);
                bfr[n][kk] = *reinterpret_cast<const v8bf*>(&Bs[r * 64 + slot * 8]);
            }
        if (t + 1 < NT) CHUNK1(cur ^ 1, t + 1);   // B2,B3 of next tile (region dead since beta(t-1))
        __builtin_amdgcn_s_barrier();
        asm volatile("s_waitcnt lgkmcnt(0)" ::: "memory");
        __builtin_amdgcn_sched_barrier(0);
        __builtin_amdgcn_s_setprio(1);
#pragma unroll
        for (int kk = 0; kk < 2; ++kk)
#pragma unroll
            for (int m = 0; m < 4; ++m)
#pragma unroll
                for (int n = 0; n < 2; ++n)
                    acc[0][m][n] = __builtin_amdgcn_mfma_f32_16x16x32_bf16(
                        af[m][kk], bfr[n][kk], acc[0][m][n], 0, 0, 0);
        __builtin_amdgcn_s_setprio(0);
        if (t + 1 < NT)
            asm volatile("s_waitcnt vmcnt(6)" ::: "memory");   // drains c1(t) -> beta can read
        else
            asm volatile("s_waitcnt vmcnt(0)" ::: "memory");   // t==NT-1: drain c1(NT-1)
        __builtin_amdgcn_s_barrier();
        __builtin_amdgcn_sched_barrier(0);

        // ======== phase beta: nh=1 (B rows 128-255; A reused from regs) ========
#pragma unroll
        for (int n = 0; n < 2; ++n)
#pragma unroll
            for (int kk = 0; kk < 2; ++kk) {
                const int r = 128 + wc * 32 + n * 16 + l16;
                const int slot = (kk * 4 + l4) ^ (l16 & 7);
                bfr[n][kk] = *reinterpret_cast<const v8bf*>(&Bs[r * 64 + slot * 8]);
            }
        if (t + 2 < NT) CHUNK0(cur, t + 2);   // A,B0,B1 regions of cur are dead after alpha's barrier
        __builtin_amdgcn_s_barrier();
        asm volatile("s_waitcnt lgkmcnt(0)" ::: "memory");
        __builtin_amdgcn_sched_barrier(0);
        __builtin_amdgcn_s_setprio(1);
#pragma unroll
        for (int kk = 0; kk < 2; ++kk)
#pragma unroll
            for (int m = 0; m < 4; ++m)
#pragma unroll
                for (int n = 0; n < 2; ++n)
                    acc[1][m][n] = __builtin_amdgcn_mfma_f32_16x16x32_bf16(
                        af[m][kk], bfr[n][kk], acc[1][m][n], 0, 0, 0);
        __builtin_amdgcn_s_setprio(0);
        if (t + 2 < NT)
            asm volatile("s_waitcnt vmcnt(6)" ::: "memory");   // drains c0(t+1)
        else if (t + 1 < NT)
            asm volatile("s_waitcnt vmcnt(2)" ::: "memory");   // t==NT-2: drain c0(NT-1)
        __builtin_amdgcn_s_barrier();
        __builtin_amdgcn_sched_barrier(0);
    }
#undef CHUNK0
#undef CHUNK1

    // Epilogue. C/D layout: col = lane&15, row = (lane>>4)*4 + j
#pragma unroll
    for (int nh = 0; nh < 2; ++nh)
#pragma unroll
        for (int m = 0; m < 4; ++m)
#pragma unroll
            for (int n = 0; n < 2; ++n) {
                const int r0 = bm * 128 + wr * 64 + m * 16 + l4 * 4;
                const int c0 = bn * 256 + nh * 128 + wc * 32 + n * 16 + l16;
                if (OUTF32) {
                    float* Cf = (float*)Cv;
                    const float bv = bias[c0];
#pragma unroll
                    for (int j = 0; j < 4; ++j)
                        Cf[(size_t)(r0 + j) * Ndim + c0] = acc[nh][m][n][j] + bv;
                } else {
                    ushort* Cb = (ushort*)Cv;
#pragma unroll
                    for (int j = 0; j < 4; ++j)
                        Cb[(size_t)(r0 + j) * Ndim + c0] = f2bf(acc[nh][m][n][j]);
                }
            }
}

// ---------------- Flash attention v3 (causal, balanced split-row binning) ----------------
__global__ __launch_bounds__(256, 2) void flash_kernel(const ushort* __restrict__ qkv,
                                                       const ushort* __restrict__ vt,
                                                       ushort* __restrict__ ao) {
    __shared__ __align__(16) ushort Kl[2][64 * 128];   // [kv][d], 16B d-chunks XOR-swizzled
    __shared__ __align__(16) ushort Vl[2][128 * 64];   // [d][kv], 16B kv-chunks XOR-swizzled
    __shared__ __align__(16) ushort Pl[128 * 64];      // [slot][kv], XOR-swizzled

    const int xi = blockIdx.x;
    const int ti = (xi & 1) ? (xi >> 1) : (15 - (xi >> 1));  // heavy/light interleave
    const int h = blockIdx.y;
    const int b = blockIdx.z;
    const int tid = threadIdx.x;
    const int lane = tid & 63;
    const int wv = tid >> 6;
    const int l4 = lane >> 4, l16 = lane & 15;

    const int rbs[2]  = {ti * 64 + wv * 16, TDIM - 64 * (ti + 1) + wv * 16};  // block-local T rows
    const int diag[2] = {ti, 31 - ti};
    const int nkt = 32 - ti;

    // Q fragments, scale folded in (A-layout: row = lane&15, k = (lane>>4)*8 + ...)
    v8bf qf[2][4];
#pragma unroll
    for (int mg = 0; mg < 2; ++mg) {
        const ushort* qp = qkv + (size_t)(b * TDIM + rbs[mg] + l16) * E3 + h * HD + l4 * 8;
#pragma unroll
        for (int d0 = 0; d0 < 4; ++d0) {
            v8bf r = *reinterpret_cast<const v8bf*>(qp + d0 * 32);
            v8bf o;
#pragma unroll
            for (int e = 0; e < 8; ++e) {
                const float f = __uint_as_float(((uint32_t)(ushort)r[e]) << 16) * 0.08838834764831845f;
                o[e] = (short)f2bf(f);
            }
            qf[mg][d0] = o;
        }
    }

    float mrun[2][4], lrun[2][4];
#pragma unroll
    for (int mg = 0; mg < 2; ++mg)
#pragma unroll
        for (int j = 0; j < 4; ++j) { mrun[mg][j] = -1e30f; lrun[mg][j] = 0.0f; }
    v4f oacc[2][8] = {};

    const ushort* kbase = qkv + (size_t)(b * TDIM) * E3 + EDIM + h * HD;
    const ushort* vbase = vt + (size_t)((b * 16 + h) * HD) * TDIM;

#define STAGE(BUF, KT)                                                                        \
    do {                                                                                      \
        _Pragma("unroll") for (int i = 0; i < 4; ++i) {                                       \
            const int c = i * 256 + tid;                                                      \
            const int row = c >> 4;                                                           \
            const int dc = (c & 15) ^ (row & 7);                                              \
            gload16(kbase + (size_t)((KT) * 64 + row) * E3 + dc * 8,                          \
                    &Kl[BUF][(i * 256 + wv * 64) * 8]);                                       \
        }                                                                                     \
        _Pragma("unroll") for (int i = 0; i < 4; ++i) {                                       \
            const int c = i * 256 + tid;                                                      \
            const int row = c >> 3;                                                           \
            const int jc = (c & 7) ^ (row & 7);                                               \
            gload16(vbase + (size_t)row * TDIM + (KT) * 64 + jc * 8,                          \
                    &Vl[BUF][(i * 256 + wv * 64) * 8]);                                       \
        }                                                                                     \
    } while (0)

    STAGE(0, 0);
    __syncthreads();
    int cur = 0;

    for (int kt = 0; kt < nkt; ++kt) {
        if (kt + 1 < nkt) STAGE(cur ^ 1, kt + 1);   // prefetch overlaps compute

        const bool act0 = (kt <= diag[0]);          // mg0 active until its diagonal
        const ushort* Kb = &Kl[cur][0];
        const ushort* Vb = &Vl[cur][0];

        // ---- S = Q @ K^T ----
        v4f s[2][4] = {};
#pragma unroll
        for (int d0 = 0; d0 < 4; ++d0) {
            v8bf kf[4];
#pragma unroll
            for (int kvn = 0; kvn < 4; ++kvn) {
                const int r = kvn * 16 + l16;
                const int slot = (d0 * 4 + l4) ^ (r & 7);
                kf[kvn] = *reinterpret_cast<const v8bf*>(&Kb[r * 128 + slot * 8]);
            }
#pragma unroll
            for (int kvn = 0; kvn < 4; ++kvn) {
                if (act0)
                    s[0][kvn] = __builtin_amdgcn_mfma_f32_16x16x32_bf16(qf[0][d0], kf[kvn], s[0][kvn], 0, 0, 0);
                s[1][kvn] = __builtin_amdgcn_mfma_f32_16x16x32_bf16(qf[1][d0], kf[kvn], s[1][kvn], 0, 0, 0);
            }
        }

        // ---- per-group softmax + P write ----
#pragma unroll
        for (int mg = 0; mg < 2; ++mg) {
            if (mg == 0 && !act0) continue;

            float sv[4][4];
#pragma unroll
            for (int kvn = 0; kvn < 4; ++kvn)
#pragma unroll
                for (int j = 0; j < 4; ++j)
                    sv[kvn][j] = s[mg][kvn][j];

            if (kt == diag[mg]) {  // diagonal tile mask (block-local T coords)
                const int rg = rbs[mg] + l4 * 4;
#pragma unroll
                for (int kvn = 0; kvn < 4; ++kvn) {
                    const int cg = kt * 64 + kvn * 16 + l16;
#pragma unroll
                    for (int j = 0; j < 4; ++j)
                        if (cg > rg + j) sv[kvn][j] = -__builtin_inff();
                }
            }

            // row max (row spans the 16-lane group)
            float pm[4], dmax = -1e30f;
#pragma unroll
            for (int j = 0; j < 4; ++j) {
                float m0 = fmaxf(fmaxf(sv[0][j], sv[1][j]), fmaxf(sv[2][j], sv[3][j]));
                m0 = fmaxf(m0, __shfl_xor(m0, 1));
                m0 = fmaxf(m0, __shfl_xor(m0, 2));
                m0 = fmaxf(m0, __shfl_xor(m0, 4));
                m0 = fmaxf(m0, __shfl_xor(m0, 8));
                pm[j] = m0;
                dmax = fmaxf(dmax, m0 - mrun[mg][j]);
            }
            if (!__all(dmax <= 8.0f)) {   // T13 defer-max: rescale only when needed
                float corr[4];
#pragma unroll
                for (int j = 0; j < 4; ++j) {
                    const float mn = fmaxf(mrun[mg][j], pm[j]);
                    corr[j] = __expf(mrun[mg][j] - mn);
                    mrun[mg][j] = mn;
                    lrun[mg][j] *= corr[j];
                }
#pragma unroll
                for (int n = 0; n < 8; ++n)
#pragma unroll
                    for (int j = 0; j < 4; ++j)
                        oacc[mg][n][j] *= corr[j];
            }

            float p[4][4];
#pragma unroll
            for (int kvn = 0; kvn < 4; ++kvn)
#pragma unroll
                for (int j = 0; j < 4; ++j)
                    p[kvn][j] = __expf(sv[kvn][j] - mrun[mg][j]);
#pragma unroll
            for (int j = 0; j < 4; ++j)
                lrun[mg][j] += p[0][j] + p[1][j] + p[2][j] + p[3][j];

            // P -> LDS (swizzled), same-wave slots only
            const int row = wv * 32 + mg * 16 + l4 * 4;
#pragma unroll
            for (int kvn = 0; kvn < 4; ++kvn) {
                const int cc = kvn * 2 + (l16 >> 3);
#pragma unroll
                for (int j = 0; j < 4; ++j) {
                    const int r = row + j;
                    Pl[r * 64 + ((cc ^ (r & 7)) * 8) + (l16 & 7)] = f2bf(p[kvn][j]);
                }
            }
        }

        // ---- O += P @ V ----
#pragma unroll
        for (int kk = 0; kk < 2; ++kk) {
            v8bf pf[2];
#pragma unroll
            for (int mg = 0; mg < 2; ++mg) {
                if (mg == 0 && !act0) continue;
                const int r = wv * 32 + mg * 16 + l16;
                const int slot = (kk * 4 + l4) ^ (r & 7);
                pf[mg] = *reinterpret_cast<const v8bf*>(&Pl[r * 64 + slot * 8]);
            }
#pragma unroll
            for (int n = 0; n < 8; ++n) {
                const int dr = n * 16 + l16;
                const int slot = (kk * 4 + l4) ^ (dr & 7);
                v8bf vf = *reinterpret_cast<const v8bf*>(&Vb[dr * 64 + slot * 8]);
                if (act0)
                    oacc[0][n] = __builtin_amdgcn_mfma_f32_16x16x32_bf16(pf[0], vf, oacc[0][n], 0, 0, 0);
                oacc[1][n] = __builtin_amdgcn_mfma_f32_16x16x32_bf16(pf[1], vf, oacc[1][n], 0, 0, 0);
            }
        }
        __syncthreads();
        cur ^= 1;
    }
#undef STAGE

    // ---- epilogue: finish l reduction, normalize, store ----
#pragma unroll
    for (int mg = 0; mg < 2; ++mg) {
        float inv[4];
#pragma unroll
        for (int j = 0; j < 4; ++j) {
            float l = lrun[mg][j];
            l += __shfl_xor(l, 1);
            l += __shfl_xor(l, 2);
            l += __shfl_xor(l, 4);
            l += __shfl_xor(l, 8);
            inv[j] = 1.0f / l;
        }
        ushort* aop = ao + (size_t)(b * TDIM + rbs[mg] + l4 * 4) * EDIM + h * HD + l16;
#pragma unroll
        for (int n = 0; n < 8; ++n)
#pragma unroll
            for (int j = 0; j < 4; ++j)
                aop[(size_t)j * EDIM + n * 16] = f2bf(oacc[mg][n][j] * inv[j]);
    }
}

// ---------------- launcher ----------------
extern "C" void kernel_launch(void* const* d_in, const int* in_sizes, int n_in,
                              void* d_out, int out_size, void* d_ws, size_t ws_size,
                              hipStream_t stream) {
    (void)in_sizes; (void)n_in; (void)out_size; (void)ws_size;
    const float* x     = (const float*)d_in[0];
    const float* w_qkv = (const float*)d_in[1];
    const float* w_out = (const float*)d_in[2];
    const float* b_out = (const float*)d_in[3];

    uint8_t* ws = (uint8_t*)d_ws;
    ushort* qkv   = (ushort*)(ws);
    ushort* woutT = (ushort*)(ws + 50331648u);
    ushort* xb    = (ushort*)(ws + 58720256u);
    ushort* wqkvT = (ushort*)(ws + 75497472u);
    ushort* vtb   = xb;     // reuse after GEMM1 consumed xb
    ushort* ao    = wqkvT;  // reuse after GEMM1 consumed wqkvT

    cvtx_kernel<<<2048, 256, 0, stream>>>(x, xb, MROWS * EDIM);
    tcvt_kernel<<<dim3(E3 / 32, EDIM / 32), 256, 0, stream>>>(w_qkv, wqkvT, EDIM, E3);
    tcvt_kernel<<<dim3(EDIM / 32, EDIM / 32), 256, 0, stream>>>(w_out, woutT, EDIM, EDIM);

    gemm2p_kernel<0><<<(MROWS / 128) * (E3 / 256), 512, 0, stream>>>(
        xb, wqkvT, (void*)qkv, nullptr, MROWS, E3, EDIM);

    vtrans_kernel<<<dim3(TDIM / 32, HD / 32, BATCH * NH), 256, 0, stream>>>(qkv, vtb);

    flash_kernel<<<dim3(16, NH, BATCH), 256, 0, stream>>>(qkv, vtb, ao);

    gemm2p_kernel<1><<<(MROWS / 128) * (EDIM / 256), 512, 0, stream>>>(
        ao, woutT, d_out, b_out, MROWS, EDIM, EDIM);
}

// Round 7
// 256.352 us; speedup vs baseline: 1.1275x; 1.0727x over previous
//
#include <hip/hip_runtime.h>
#include <stdint.h>

// Problem constants
#define BATCH 2
#define TDIM 2048
#define EDIM 2048
#define NH 16
#define HD 128
#define E3 6144
#define MROWS 4096  // BATCH*TDIM
#define QKS 4096    // row stride of compacted Q|K buffer

typedef short v8bf __attribute__((ext_vector_type(8)));   // 8 bf16 bit patterns (4 VGPRs)
typedef float v4f  __attribute__((ext_vector_type(4)));

typedef __attribute__((address_space(3))) uint8_t lds_u8;
typedef __attribute__((address_space(1))) uint8_t glb_u8;

__device__ __forceinline__ void gload16(const void* g, void* l) {
    __builtin_amdgcn_global_load_lds((const glb_u8*)g, (lds_u8*)l, 16, 0, 0);
}

__device__ __forceinline__ ushort f2bf(float f) {
    uint32_t u = __float_as_uint(f);
    return (ushort)((u + 0x7fffu + ((u >> 16) & 1u)) >> 16);  // RNE
}

// ---------------- fused preprocessing: tcvt(w_qkv) + tcvt(w_out) + cvtx(x) ----------------
__device__ __forceinline__ void tcvt_body(const float* __restrict__ in, ushort* __restrict__ out,
                                          int R, int C, int tcb, int trb, int tid) {
    __shared__ float t[32][33];
    const int tc = tcb * 32, tr = trb * 32;
    const int row = tid >> 3, c4 = (tid & 7) * 4;
    const float4 v = *reinterpret_cast<const float4*>(in + (size_t)(tr + row) * C + tc + c4);
    t[row][c4] = v.x; t[row][c4 + 1] = v.y; t[row][c4 + 2] = v.z; t[row][c4 + 3] = v.w;
    __syncthreads();
    const int oc = tid >> 3, r4 = (tid & 7) * 4;
    ushort4 o = make_ushort4(f2bf(t[r4][oc]), f2bf(t[r4 + 1][oc]),
                             f2bf(t[r4 + 2][oc]), f2bf(t[r4 + 3][oc]));
    *reinterpret_cast<ushort4*>(out + (size_t)(tc + oc) * R + tr + r4) = o;
}

#define NB_T1 12288   // (6144/32)*(2048/32)
#define NB_T2 4096    // (2048/32)*(2048/32)
#define NB_CV 2048

__global__ void prep_kernel(const float* __restrict__ x, const float* __restrict__ w_qkv,
                            const float* __restrict__ w_out, ushort* __restrict__ xb,
                            ushort* __restrict__ wqkvT, ushort* __restrict__ woutT) {
    const int bid = blockIdx.x;
    const int tid = threadIdx.x;
    if (bid < NB_T1) {
        tcvt_body(w_qkv, wqkvT, EDIM, E3, bid % (E3 / 32), bid / (E3 / 32), tid);
    } else if (bid < NB_T1 + NB_T2) {
        const int b2 = bid - NB_T1;
        tcvt_body(w_out, woutT, EDIM, EDIM, b2 % (EDIM / 32), b2 / (EDIM / 32), tid);
    } else {
        const int b3 = bid - NB_T1 - NB_T2;
        int i = (b3 * 256 + tid) * 4;
        const int stride = NB_CV * 256 * 4;
        const int n = MROWS * EDIM;
        for (; i < n; i += stride) {
            const float4 v = *reinterpret_cast<const float4*>(x + i);
            ushort4 o = make_ushort4(f2bf(v.x), f2bf(v.y), f2bf(v.z), f2bf(v.w));
            *reinterpret_cast<ushort4*>(xb + i) = o;
        }
    }
}

// ---------------- bf16 GEMM (128x128, m97-structure, proven 892 TF) ----------------
// MODE 0: bf16 C. MODE 1: f32 C + bias. MODE 2: qkv-split -> Q,K cols to qk (stride QKS),
//         V cols (bn>=32) transposed per-head into vt[bh][d][t].
template <int MODE>
__global__ void gemm_kernel(const ushort* __restrict__ A, const ushort* __restrict__ Bt,
                            void* __restrict__ Cv, const float* __restrict__ bias,
                            ushort* __restrict__ vtout,
                            int Mdim, int Ndim, int Kdim) {
    __shared__ __align__(16) ushort As[128 * 64];
    __shared__ __align__(16) ushort Bs[128 * 64];
    const int tid = threadIdx.x;
    const int lane = tid & 63;
    const int wv = tid >> 6;
    const int l4 = lane >> 4, l16 = lane & 15;
    const int nbn = Ndim >> 7;
    const int nwg = (Mdim >> 7) * nbn;
    int bid = blockIdx.x;
    bid = (bid & 7) * (nwg >> 3) + (bid >> 3);   // XCD swizzle (nwg % 8 == 0)
    const int bm = bid / nbn, bn = bid % nbn;
    const int wr = wv >> 1, wc = wv & 1;

    const ushort* Abase = A + (size_t)(bm * 128) * Kdim;
    const ushort* Bbase = Bt + (size_t)(bn * 128) * Kdim;

    v4f acc[4][4] = {};

    for (int k0 = 0; k0 < Kdim; k0 += 64) {
#pragma unroll
        for (int i = 0; i < 4; ++i) {
            const int c = i * 256 + tid;
            const int row = c >> 3;
            const int kc = (c & 7) ^ (row & 7);    // pre-swizzled global source
            gload16(Abase + (size_t)row * Kdim + k0 + kc * 8, &As[(i * 256 + wv * 64) * 8]);
        }
#pragma unroll
        for (int i = 0; i < 4; ++i) {
            const int c = i * 256 + tid;
            const int row = c >> 3;
            const int kc = (c & 7) ^ (row & 7);
            gload16(Bbase + (size_t)row * Kdim + k0 + kc * 8, &Bs[(i * 256 + wv * 64) * 8]);
        }
        __syncthreads();
#pragma unroll
        for (int kk = 0; kk < 2; ++kk) {
            v8bf af[4], bfr[4];
#pragma unroll
            for (int m = 0; m < 4; ++m) {
                const int r = wr * 64 + m * 16 + l16;
                const int slot = (kk * 4 + l4) ^ (r & 7);
                af[m] = *reinterpret_cast<const v8bf*>(&As[r * 64 + slot * 8]);
            }
#pragma unroll
            for (int n = 0; n < 4; ++n) {
                const int r = wc * 64 + n * 16 + l16;
                const int slot = (kk * 4 + l4) ^ (r & 7);
                bfr[n] = *reinterpret_cast<const v8bf*>(&Bs[r * 64 + slot * 8]);
            }
#pragma unroll
            for (int m = 0; m < 4; ++m)
#pragma unroll
                for (int n = 0; n < 4; ++n)
                    acc[m][n] = __builtin_amdgcn_mfma_f32_16x16x32_bf16(af[m], bfr[n], acc[m][n], 0, 0, 0);
        }
        __syncthreads();
    }

    // Epilogue. C/D layout: col = lane&15, row = (lane>>4)*4 + j
    const int r0 = bm * 128 + wr * 64 + l4 * 4;
    const int c0 = bn * 128 + wc * 64 + l16;
    if (MODE == 1) {
        float* Cf = (float*)Cv;
#pragma unroll
        for (int n = 0; n < 4; ++n) {
            const float bv = bias[c0 + n * 16];
#pragma unroll
            for (int m = 0; m < 4; ++m)
#pragma unroll
                for (int j = 0; j < 4; ++j)
                    Cf[(size_t)(r0 + m * 16 + j) * Ndim + c0 + n * 16] = acc[m][n][j] + bv;
        }
    } else if (MODE == 2 && bn >= 32) {
        // V columns: write transposed into vt[(b*16+h)*128 + d][t]
        const int h = bn - 32;
#pragma unroll
        for (int m = 0; m < 4; ++m) {
            const int r = r0 + m * 16;           // global row = b*2048 + t
            const int b = r >> 11, t0 = r & 2047;
#pragma unroll
            for (int n = 0; n < 4; ++n) {
                const int dcol = wc * 64 + n * 16 + l16;
                ushort* vp = vtout + (size_t)((b * 16 + h) * 128 + dcol) * TDIM + t0;
#pragma unroll
                for (int j = 0; j < 4; ++j)
                    vp[j] = f2bf(acc[m][n][j]);
            }
        }
    } else {
        // MODE 0, or MODE 2 Q/K columns (row stride QKS for MODE 2)
        const int cstride = (MODE == 2) ? QKS : Ndim;
        ushort* Cb = (ushort*)Cv;
#pragma unroll
        for (int n = 0; n < 4; ++n)
#pragma unroll
            for (int m = 0; m < 4; ++m)
#pragma unroll
                for (int j = 0; j < 4; ++j)
                    Cb[(size_t)(r0 + m * 16 + j) * cstride + c0 + n * 16] = f2bf(acc[m][n][j]);
    }
}

// ---------------- Flash attention v3 (causal, balanced split-row binning) ----------------
// qk [4096][4096] bf16 (Q cols 0..2047, K cols 2048..4095); vt [bh][128][2048]; ao [4096][2048]
__global__ __launch_bounds__(256, 2) void flash_kernel(const ushort* __restrict__ qk,
                                                       const ushort* __restrict__ vt,
                                                       ushort* __restrict__ ao) {
    __shared__ __align__(16) ushort Kl[2][64 * 128];   // [kv][d], 16B d-chunks XOR-swizzled
    __shared__ __align__(16) ushort Vl[2][128 * 64];   // [d][kv], 16B kv-chunks XOR-swizzled
    __shared__ __align__(16) ushort Pl[128 * 64];      // [slot][kv], XOR-swizzled

    const int xi = blockIdx.x;
    const int ti = (xi & 1) ? (xi >> 1) : (15 - (xi >> 1));  // heavy/light interleave
    const int h = blockIdx.y;
    const int b = blockIdx.z;
    const int tid = threadIdx.x;
    const int lane = tid & 63;
    const int wv = tid >> 6;
    const int l4 = lane >> 4, l16 = lane & 15;

    const int rbs[2]  = {ti * 64 + wv * 16, TDIM - 64 * (ti + 1) + wv * 16};  // block-local T rows
    const int diag[2] = {ti, 31 - ti};
    const int nkt = 32 - ti;

    // Q fragments, scale folded in (A-layout: row = lane&15, k = (lane>>4)*8 + ...)
    v8bf qf[2][4];
#pragma unroll
    for (int mg = 0; mg < 2; ++mg) {
        const ushort* qp = qk + (size_t)(b * TDIM + rbs[mg] + l16) * QKS + h * HD + l4 * 8;
#pragma unroll
        for (int d0 = 0; d0 < 4; ++d0) {
            v8bf r = *reinterpret_cast<const v8bf*>(qp + d0 * 32);
            v8bf o;
#pragma unroll
            for (int e = 0; e < 8; ++e) {
                const float f = __uint_as_float(((uint32_t)(ushort)r[e]) << 16) * 0.08838834764831845f;
                o[e] = (short)f2bf(f);
            }
            qf[mg][d0] = o;
        }
    }

    float mrun[2][4], lrun[2][4];
#pragma unroll
    for (int mg = 0; mg < 2; ++mg)
#pragma unroll
        for (int j = 0; j < 4; ++j) { mrun[mg][j] = -1e30f; lrun[mg][j] = 0.0f; }
    v4f oacc[2][8] = {};

    const ushort* kbase = qk + (size_t)(b * TDIM) * QKS + EDIM + h * HD;
    const ushort* vbase = vt + (size_t)((b * 16 + h) * HD) * TDIM;

#define STAGE(BUF, KT)                                                                        \
    do {                                                                                      \
        _Pragma("unroll") for (int i = 0; i < 4; ++i) {                                       \
            const int c = i * 256 + tid;                                                      \
            const int row = c >> 4;                                                           \
            const int dc = (c & 15) ^ (row & 7);                                              \
            gload16(kbase + (size_t)((KT) * 64 + row) * QKS + dc * 8,                         \
                    &Kl[BUF][(i * 256 + wv * 64) * 8]);                                       \
        }                                                                                     \
        _Pragma("unroll") for (int i = 0; i < 4; ++i) {                                       \
            const int c = i * 256 + tid;                                                      \
            const int row = c >> 3;                                                           \
            const int jc = (c & 7) ^ (row & 7);                                               \
            gload16(vbase + (size_t)row * TDIM + (KT) * 64 + jc * 8,                          \
                    &Vl[BUF][(i * 256 + wv * 64) * 8]);                                       \
        }                                                                                     \
    } while (0)

    STAGE(0, 0);
    __syncthreads();
    int cur = 0;

    for (int kt = 0; kt < nkt; ++kt) {
        if (kt + 1 < nkt) STAGE(cur ^ 1, kt + 1);   // prefetch overlaps compute

        const bool act0 = (kt <= diag[0]);          // mg0 active until its diagonal
        const ushort* Kb = &Kl[cur][0];
        const ushort* Vb = &Vl[cur][0];

        // ---- S = Q @ K^T ----
        v4f s[2][4] = {};
#pragma unroll
        for (int d0 = 0; d0 < 4; ++d0) {
            v8bf kf[4];
#pragma unroll
            for (int kvn = 0; kvn < 4; ++kvn) {
                const int r = kvn * 16 + l16;
                const int slot = (d0 * 4 + l4) ^ (r & 7);
                kf[kvn] = *reinterpret_cast<const v8bf*>(&Kb[r * 128 + slot * 8]);
            }
#pragma unroll
            for (int kvn = 0; kvn < 4; ++kvn) {
                if (act0)
                    s[0][kvn] = __builtin_amdgcn_mfma_f32_16x16x32_bf16(qf[0][d0], kf[kvn], s[0][kvn], 0, 0, 0);
                s[1][kvn] = __builtin_amdgcn_mfma_f32_16x16x32_bf16(qf[1][d0], kf[kvn], s[1][kvn], 0, 0, 0);
            }
        }

        // ---- per-group softmax + P write ----
#pragma unroll
        for (int mg = 0; mg < 2; ++mg) {
            if (mg == 0 && !act0) continue;

            float sv[4][4];
#pragma unroll
            for (int kvn = 0; kvn < 4; ++kvn)
#pragma unroll
                for (int j = 0; j < 4; ++j)
                    sv[kvn][j] = s[mg][kvn][j];

            if (kt == diag[mg]) {  // diagonal tile mask (block-local T coords)
                const int rg = rbs[mg] + l4 * 4;
#pragma unroll
                for (int kvn = 0; kvn < 4; ++kvn) {
                    const int cg = kt * 64 + kvn * 16 + l16;
#pragma unroll
                    for (int j = 0; j < 4; ++j)
                        if (cg > rg + j) sv[kvn][j] = -__builtin_inff();
                }
            }

            // row max (row spans the 16-lane group)
            float pm[4], dmax = -1e30f;
#pragma unroll
            for (int j = 0; j < 4; ++j) {
                float m0 = fmaxf(fmaxf(sv[0][j], sv[1][j]), fmaxf(sv[2][j], sv[3][j]));
                m0 = fmaxf(m0, __shfl_xor(m0, 1));
                m0 = fmaxf(m0, __shfl_xor(m0, 2));
                m0 = fmaxf(m0, __shfl_xor(m0, 4));
                m0 = fmaxf(m0, __shfl_xor(m0, 8));
                pm[j] = m0;
                dmax = fmaxf(dmax, m0 - mrun[mg][j]);
            }
            if (!__all(dmax <= 8.0f)) {   // T13 defer-max: rescale only when needed
                float corr[4];
#pragma unroll
                for (int j = 0; j < 4; ++j) {
                    const float mn = fmaxf(mrun[mg][j], pm[j]);
                    corr[j] = __expf(mrun[mg][j] - mn);
                    mrun[mg][j] = mn;
                    lrun[mg][j] *= corr[j];
                }
#pragma unroll
                for (int n = 0; n < 8; ++n)
#pragma unroll
                    for (int j = 0; j < 4; ++j)
                        oacc[mg][n][j] *= corr[j];
            }

            float p[4][4];
#pragma unroll
            for (int kvn = 0; kvn < 4; ++kvn)
#pragma unroll
                for (int j = 0; j < 4; ++j)
                    p[kvn][j] = __expf(sv[kvn][j] - mrun[mg][j]);
#pragma unroll
            for (int j = 0; j < 4; ++j)
                lrun[mg][j] += p[0][j] + p[1][j] + p[2][j] + p[3][j];

            // P -> LDS (swizzled), same-wave slots only
            const int row = wv * 32 + mg * 16 + l4 * 4;
#pragma unroll
            for (int kvn = 0; kvn < 4; ++kvn) {
                const int cc = kvn * 2 + (l16 >> 3);
#pragma unroll
                for (int j = 0; j < 4; ++j) {
                    const int r = row + j;
                    Pl[r * 64 + ((cc ^ (r & 7)) * 8) + (l16 & 7)] = f2bf(p[kvn][j]);
                }
            }
        }

        // ---- O += P @ V ----
#pragma unroll
        for (int kk = 0; kk < 2; ++kk) {
            v8bf pf[2];
#pragma unroll
            for (int mg = 0; mg < 2; ++mg) {
                if (mg == 0 && !act0) continue;
                const int r = wv * 32 + mg * 16 + l16;
                const int slot = (kk * 4 + l4) ^ (r & 7);
                pf[mg] = *reinterpret_cast<const v8bf*>(&Pl[r * 64 + slot * 8]);
            }
#pragma unroll
            for (int n = 0; n < 8; ++n) {
                const int dr = n * 16 + l16;
                const int slot = (kk * 4 + l4) ^ (dr & 7);
                v8bf vf = *reinterpret_cast<const v8bf*>(&Vb[dr * 64 + slot * 8]);
                if (act0)
                    oacc[0][n] = __builtin_amdgcn_mfma_f32_16x16x32_bf16(pf[0], vf, oacc[0][n], 0, 0, 0);
                oacc[1][n] = __builtin_amdgcn_mfma_f32_16x16x32_bf16(pf[1], vf, oacc[1][n], 0, 0, 0);
            }
        }
        __syncthreads();
        cur ^= 1;
    }
#undef STAGE

    // ---- epilogue: finish l reduction, normalize, store ----
#pragma unroll
    for (int mg = 0; mg < 2; ++mg) {
        float inv[4];
#pragma unroll
        for (int j = 0; j < 4; ++j) {
            float l = lrun[mg][j];
            l += __shfl_xor(l, 1);
            l += __shfl_xor(l, 2);
            l += __shfl_xor(l, 4);
            l += __shfl_xor(l, 8);
            inv[j] = 1.0f / l;
        }
        ushort* aop = ao + (size_t)(b * TDIM + rbs[mg] + l4 * 4) * EDIM + h * HD + l16;
#pragma unroll
        for (int n = 0; n < 8; ++n)
#pragma unroll
            for (int j = 0; j < 4; ++j)
                aop[(size_t)j * EDIM + n * 16] = f2bf(oacc[mg][n][j] * inv[j]);
    }
}

// ---------------- launcher ----------------
extern "C" void kernel_launch(void* const* d_in, const int* in_sizes, int n_in,
                              void* d_out, int out_size, void* d_ws, size_t ws_size,
                              hipStream_t stream) {
    (void)in_sizes; (void)n_in; (void)out_size; (void)ws_size;
    const float* x     = (const float*)d_in[0];
    const float* w_qkv = (const float*)d_in[1];
    const float* w_out = (const float*)d_in[2];
    const float* b_out = (const float*)d_in[3];

    uint8_t* ws = (uint8_t*)d_ws;
    // layout (bytes):
    //   qk    @ 0         : 4096*4096*2 = 33554432   (Q|K, row stride 4096)
    //   vt    @ 33554432  : 32*128*2048*2 = 16777216 (V transposed per head)
    //   woutT @ 50331648  : 2048*2048*2 =  8388608
    //   xb    @ 58720256  : 4096*2048*2 = 16777216
    //   wqkvT @ 75497472  : 6144*2048*2 = 25165824   (aliased by ao after GEMM1)
    ushort* qk    = (ushort*)(ws);
    ushort* vtb   = (ushort*)(ws + 33554432u);
    ushort* woutT = (ushort*)(ws + 50331648u);
    ushort* xb    = (ushort*)(ws + 58720256u);
    ushort* wqkvT = (ushort*)(ws + 75497472u);
    ushort* ao    = wqkvT;  // reuse after GEMM1 consumed wqkvT

    prep_kernel<<<NB_T1 + NB_T2 + NB_CV, 256, 0, stream>>>(x, w_qkv, w_out, xb, wqkvT, woutT);

    gemm_kernel<2><<<(MROWS / 128) * (E3 / 128), 256, 0, stream>>>(
        xb, wqkvT, (void*)qk, nullptr, vtb, MROWS, E3, EDIM);

    flash_kernel<<<dim3(16, NH, BATCH), 256, 0, stream>>>(qk, vtb, ao);

    gemm_kernel<1><<<(MROWS / 128) * (EDIM / 128), 256, 0, stream>>>(
        ao, woutT, d_out, b_out, nullptr, MROWS, EDIM, EDIM);
}